// Round 11
// baseline (198.526 us; speedup 1.0000x reference)
//
#include <hip/hip_runtime.h>
#include <math.h>

#define NN 50000
#define KK 16
#define FIN 140
#define HH 8
#define HID 128

typedef __attribute__((ext_vector_type(8))) short short8;   // 8 bf16 = 4 VGPRs
typedef __attribute__((ext_vector_type(4))) float f32x4;    // MFMA acc

__device__ inline unsigned short f2bf(float f) {            // RNE fp32->bf16
  unsigned int u = __float_as_uint(f);
  return (unsigned short)((u + 0x7fffu + ((u >> 16) & 1u)) >> 16);
}
__device__ inline float bf2f(unsigned short h) {
  return __uint_as_float(((unsigned int)h) << 16);
}

// Build W^T A-operand fragment tables (hi/lo bf16 split) for pca_w and both Ws.
__global__ __launch_bounds__(256) void prep_kernel(
    const float* __restrict__ pca_w, const float* __restrict__ Ws,
    unsigned short* __restrict__ frags) {
  const int gid = blockIdx.x * 256 + threadIdx.x;   // 208*256 = 53248 exact
  const float* W; int K; unsigned short *dh, *dl; int tid;
  if (gid < 20480)      { W = pca_w;          K = FIN; dh = frags;                 dl = dh + 20480; tid = gid; }
  else if (gid < 36864) { W = Ws;             K = HID; dh = frags + 40960;         dl = dh + 16384; tid = gid - 20480; }
  else                  { W = Ws + HID * HID; K = HID; dh = frags + 40960 + 32768; dl = dh + 16384; tid = gid - 36864; }
  const int j = tid & 7, L = (tid >> 3) & 63, ct = tid >> 9, t = ct & 7, c = ct >> 3;
  const int k = c * 32 + (L >> 4) * 8 + j;
  const int col = t * 16 + (L & 15);
  const float v = (k < K) ? W[(size_t)k * HID + col] : 0.f;
  const unsigned short h = f2bf(v);
  dh[tid] = h;
  dl[tid] = f2bf(v - bf2f(h));
}

// FUSED pca -> proj0. One 16-node tile per wave, 4 waves/block, frag chunks
// LDS-staged (R7 win). proj0's B-operand is exactly the 16 xbf rows this SAME
// wave wrote in the pca phase: s_waitcnt vmcnt(0) suffices (R2-proven).
__global__ __launch_bounds__(256) void pca_proj0(
    const float* __restrict__ feat, const unsigned short* __restrict__ frags,
    const float* __restrict__ pca_b, const float* __restrict__ b0,
    const float* __restrict__ asrc, const float* __restrict__ adst,
    unsigned short* __restrict__ xbf, unsigned short* __restrict__ hbf,
    float* __restrict__ ssrc, float* __restrict__ sdst) {
  __shared__ short8 ldsh[512];   // 8 KB: chunk's hi frags
  __shared__ short8 ldsl[512];   // 8 KB: chunk's lo frags
  const int tid = threadIdx.x;
  const int wv = ((int)blockIdx.x << 2) + (tid >> 6);
  const bool active = wv < NN / 16;               // 782*4 = 3128, 3125 valid
  const int lane = tid & 63;
  const int col = lane & 15, quad = lane >> 4;
  const int n0 = (active ? wv : 0) * 16;
  f32x4 acc[8];
#pragma unroll
  for (int t = 0; t < 8; ++t) acc[t] = (f32x4){0.f, 0.f, 0.f, 0.f};
  // ---------------- phase 1: x0 = relu(feat @ pca_w + b) ----------------
  {
    const float* brow = feat + (size_t)(n0 + col) * FIN + quad * 8;
    const short8* gfh = (const short8*)frags;             // pca hi
    const short8* gfl = (const short8*)(frags + 20480);   // pca lo
#pragma unroll
    for (int c = 0; c < 5; ++c) {
      __syncthreads();                            // prev chunk compute done
      ldsh[tid]       = gfh[c * 512 + tid];
      ldsh[tid + 256] = gfh[c * 512 + tid + 256];
      ldsl[tid]       = gfl[c * 512 + tid];
      ldsl[tid + 256] = gfl[c * 512 + tid + 256];
      float4 a0, a1;
      if (c < 4) {
        a0 = *(const float4*)(brow + c * 32);
        a1 = *(const float4*)(brow + c * 32 + 4);
      } else {  // chunk 4: k = 128 + quad*8 + j, valid only k < 140
        a0 = make_float4(0.f, 0.f, 0.f, 0.f); a1 = a0;
        if (quad == 0) {
          a0 = *(const float4*)(brow + 128); a1 = *(const float4*)(brow + 132);
        } else if (quad == 1) {
          a0 = *(const float4*)(brow + 128);
        }
      }
      short8 B0;
      B0[0] = (short)f2bf(a0.x); B0[1] = (short)f2bf(a0.y);
      B0[2] = (short)f2bf(a0.z); B0[3] = (short)f2bf(a0.w);
      B0[4] = (short)f2bf(a1.x); B0[5] = (short)f2bf(a1.y);
      B0[6] = (short)f2bf(a1.z); B0[7] = (short)f2bf(a1.w);
      __syncthreads();                            // chunk staged
#pragma unroll
      for (int t = 0; t < 8; ++t) {
        const short8 Ah = ldsh[t * 64 + lane];
        const short8 Al = ldsl[t * 64 + lane];
        acc[t] = __builtin_amdgcn_mfma_f32_16x16x32_bf16(Al, B0, acc[t], 0, 0, 0);
        acc[t] = __builtin_amdgcn_mfma_f32_16x16x32_bf16(Ah, B0, acc[t], 0, 0, 0);
      }
    }
  }
  // pca epilogue: relu+bias -> bf16 -> xbf rows. Guarded stores, NO early
  // return (phase-2 barriers need all waves).
  if (active) {
#pragma unroll
    for (int t = 0; t < 8; ++t) {
      const float4 bv = *(const float4*)(pca_b + t * 16 + quad * 4);
      const float v0 = fmaxf(acc[t][0] + bv.x, 0.f);
      const float v1 = fmaxf(acc[t][1] + bv.y, 0.f);
      const float v2 = fmaxf(acc[t][2] + bv.z, 0.f);
      const float v3 = fmaxf(acc[t][3] + bv.w, 0.f);
      uint2 pk;
      pk.x = (unsigned)f2bf(v0) | ((unsigned)f2bf(v1) << 16);
      pk.y = (unsigned)f2bf(v2) | ((unsigned)f2bf(v3) << 16);
      *(uint2*)&xbf[(size_t)(n0 + col) * HID + t * 16 + quad * 4] = pk;
    }
  }
  // Drain this wave's own xbf stores; reload its own 16 rows (L1-hot).
  asm volatile("s_waitcnt vmcnt(0)" ::: "memory");
  // ---------------- phase 2: h0 = x0 @ W0 + b0; s_src/s_dst ----------------
  const unsigned short* brow2 = xbf + (size_t)(n0 + col) * HID + quad * 8;
  short8 Bx[4];
#pragma unroll
  for (int c = 0; c < 4; ++c) Bx[c] = *(const short8*)(brow2 + c * 32);
#pragma unroll
  for (int t = 0; t < 8; ++t) acc[t] = (f32x4){0.f, 0.f, 0.f, 0.f};
  {
    const short8* gqh = (const short8*)(frags + 40960);           // W0 hi
    const short8* gql = (const short8*)(frags + 40960 + 16384);   // W0 lo
#pragma unroll
    for (int c = 0; c < 4; ++c) {
      __syncthreads();
      ldsh[tid]       = gqh[c * 512 + tid];
      ldsh[tid + 256] = gqh[c * 512 + tid + 256];
      ldsl[tid]       = gql[c * 512 + tid];
      ldsl[tid + 256] = gql[c * 512 + tid + 256];
      __syncthreads();
#pragma unroll
      for (int t = 0; t < 8; ++t) {
        const short8 Ah = ldsh[t * 64 + lane];
        const short8 Al = ldsl[t * 64 + lane];
        acc[t] = __builtin_amdgcn_mfma_f32_16x16x32_bf16(Al, Bx[c], acc[t], 0, 0, 0);
        acc[t] = __builtin_amdgcn_mfma_f32_16x16x32_bf16(Ah, Bx[c], acc[t], 0, 0, 0);
      }
    }
  }
  if (!active) return;
  // proj epilogue: lane holds node n0+col, out-cols t*16+quad*4+r (head == t)
#pragma unroll
  for (int t = 0; t < 8; ++t) {
    const float4 bv = *(const float4*)(b0 + t * 16 + quad * 4);
    const float4 av = *(const float4*)(asrc + t * 16 + quad * 4);
    const float4 dv = *(const float4*)(adst + t * 16 + quad * 4);
    const float v0 = acc[t][0] + bv.x;
    const float v1 = acc[t][1] + bv.y;
    const float v2 = acc[t][2] + bv.z;
    const float v3 = acc[t][3] + bv.w;
    uint2 pk;
    pk.x = (unsigned)f2bf(v0) | ((unsigned)f2bf(v1) << 16);
    pk.y = (unsigned)f2bf(v2) | ((unsigned)f2bf(v3) << 16);
    *(uint2*)&hbf[(size_t)(n0 + col) * HID + t * 16 + quad * 4] = pk;
    float ps = v0 * av.x + v1 * av.y + v2 * av.z + v3 * av.w;
    float pd = v0 * dv.x + v1 * dv.y + v2 * dv.z + v3 * dv.w;
    ps += __shfl_xor(ps, 16); ps += __shfl_xor(ps, 32);
    pd += __shfl_xor(pd, 16); pd += __shfl_xor(pd, 32);
    if (quad == 0) ssrc[(size_t)(n0 + col) * HH + t] = ps;
    if (quad == 1) sdst[(size_t)(n0 + col) * HH + t] = pd;
  }
}

// h = x@W + b (bf16 store); s_src/s_dst per head. LDS frag staging (layer 1).
__global__ __launch_bounds__(256) void proj_mfma(
    const unsigned short* __restrict__ xbf, const unsigned short* __restrict__ wfh,
    const unsigned short* __restrict__ wfl, const float* __restrict__ b,
    const float* __restrict__ asrc, const float* __restrict__ adst,
    unsigned short* __restrict__ hbf, float* __restrict__ ssrc,
    float* __restrict__ sdst) {
  __shared__ short8 ldsh[512];
  __shared__ short8 ldsl[512];
  const int tid = threadIdx.x;
  const int wv = ((int)blockIdx.x << 2) + (tid >> 6);
  const bool active = wv < NN / 16;
  const int lane = tid & 63;
  const int col = lane & 15, quad = lane >> 4;
  const int n0 = (active ? wv : 0) * 16;
  f32x4 acc[8];
#pragma unroll
  for (int t = 0; t < 8; ++t) acc[t] = (f32x4){0.f, 0.f, 0.f, 0.f};
  const unsigned short* brow = xbf + (size_t)(n0 + col) * HID + quad * 8;
  short8 B0[4];
#pragma unroll
  for (int c = 0; c < 4; ++c) B0[c] = *(const short8*)(brow + c * 32);
  const short8* gfh = (const short8*)wfh;
  const short8* gfl = (const short8*)wfl;
#pragma unroll
  for (int c = 0; c < 4; ++c) {
    __syncthreads();
    ldsh[tid]       = gfh[c * 512 + tid];
    ldsh[tid + 256] = gfh[c * 512 + tid + 256];
    ldsl[tid]       = gfl[c * 512 + tid];
    ldsl[tid + 256] = gfl[c * 512 + tid + 256];
    __syncthreads();
#pragma unroll
    for (int t = 0; t < 8; ++t) {
      const short8 Ah = ldsh[t * 64 + lane];
      const short8 Al = ldsl[t * 64 + lane];
      acc[t] = __builtin_amdgcn_mfma_f32_16x16x32_bf16(Al, B0[c], acc[t], 0, 0, 0);
      acc[t] = __builtin_amdgcn_mfma_f32_16x16x32_bf16(Ah, B0[c], acc[t], 0, 0, 0);
    }
  }
  if (!active) return;
  // lane holds node n0+col, out-cols t*16+quad*4+r (head == t)
#pragma unroll
  for (int t = 0; t < 8; ++t) {
    const float4 bv = *(const float4*)(b + t * 16 + quad * 4);
    const float4 av = *(const float4*)(asrc + t * 16 + quad * 4);
    const float4 dv = *(const float4*)(adst + t * 16 + quad * 4);
    const float v0 = acc[t][0] + bv.x;
    const float v1 = acc[t][1] + bv.y;
    const float v2 = acc[t][2] + bv.z;
    const float v3 = acc[t][3] + bv.w;
    uint2 pk;
    pk.x = (unsigned)f2bf(v0) | ((unsigned)f2bf(v1) << 16);
    pk.y = (unsigned)f2bf(v2) | ((unsigned)f2bf(v3) << 16);
    *(uint2*)&hbf[(size_t)(n0 + col) * HID + t * 16 + quad * 4] = pk;
    float ps = v0 * av.x + v1 * av.y + v2 * av.z + v3 * av.w;
    float pd = v0 * dv.x + v1 * dv.y + v2 * dv.z + v3 * dv.w;
    ps += __shfl_xor(ps, 16); ps += __shfl_xor(ps, 32);
    pd += __shfl_xor(pd, 16); pd += __shfl_xor(pd, 32);
    if (quad == 0) ssrc[(size_t)(n0 + col) * HH + t] = ps;
    if (quad == 1) sdst[(size_t)(n0 + col) * HH + t] = pd;
  }
}

// attn: ONE NODE per wave, PAIRED-ROW gathers (R11: lanes 0-31 cover even
// neighbors, 32-63 odd; each lane loads uint2 = 4 bf16 cols -> 8 fat gathers
// (512B/instr, 2 rows) instead of 16 dword gathers. Softmax topology is
// unchanged (lane = k0*8+h, xor-8/16/32 tree). PV: lane (par,l5) accumulates
// cols 4*l5..4*l5+3 over its 8 neighbors with weights p[2k+par][l5>>2]
// shuffled from the softmax layout; final __shfl_xor(32) combines halves.
template <bool LAST>
__device__ inline void attn_node(
    const int* __restrict__ nb, const unsigned int* __restrict__ hbf,
    const float* __restrict__ ssrc, const float* __restrict__ sdst,
    void* __restrict__ xout, int lane, int nid) {
  int nbv = 0;
  if (lane < KK) nbv = nb[(size_t)nid * KK + lane];
  const int par = lane >> 5;            // 0: even neighbors, 1: odd
  const int l5  = lane & 31;
  const uint2* hbf2 = (const uint2*)hbf;
  uint2 v[8];
#pragma unroll
  for (int k = 0; k < 8; ++k) {
    const int r = __shfl(nbv, 2 * k + par);
    v[k] = hbf2[(size_t)r * (HID / 4) + l5];
  }
  // softmax over 16 neighbors (proven layout: lane = k0*8 + h)
  const int h = lane & 7, k0 = lane >> 3;
  const int r0 = __shfl(nbv, k0), r1 = __shfl(nbv, k0 + 8);
  const float ss = ssrc[(size_t)nid * HH + h];
  float e0 = ss + sdst[(size_t)r0 * HH + h];
  float e1 = ss + sdst[(size_t)r1 * HH + h];
  e0 = e0 > 0.f ? e0 : 0.2f * e0;
  e1 = e1 > 0.f ? e1 : 0.2f * e1;
  float m = fmaxf(e0, e1);
  m = fmaxf(m, __shfl_xor(m, 8));
  m = fmaxf(m, __shfl_xor(m, 16));
  m = fmaxf(m, __shfl_xor(m, 32));
  float p0 = __expf(e0 - m), p1 = __expf(e1 - m);
  float s = p0 + p1;
  s += __shfl_xor(s, 8);
  s += __shfl_xor(s, 16);
  s += __shfl_xor(s, 32);
  const float inv = 1.f / s;
  p0 *= inv; p1 *= inv;
  // PV: cols 4*l5 .. 4*l5+3, head hc = l5>>2. Weight p[kk][hc] lives at lane
  // (kk&7)*8+hc as p0 (kk<8) / p1 (kk>=8); kk = 2k+par, so k<4 -> p0, k>=4 -> p1.
  const int hc = l5 >> 2;
  float a0 = 0.f, a1 = 0.f, a2 = 0.f, a3 = 0.f;
#pragma unroll
  for (int k = 0; k < 8; ++k) {
    const int kk = 2 * k + par;
    const float sel = (k < 4) ? p0 : p1;
    const float w = __shfl(sel, ((kk & 7) << 3) + hc);
    a0 = fmaf(w, __uint_as_float(v[k].x << 16), a0);
    a1 = fmaf(w, __uint_as_float(v[k].x & 0xffff0000u), a1);
    a2 = fmaf(w, __uint_as_float(v[k].y << 16), a2);
    a3 = fmaf(w, __uint_as_float(v[k].y & 0xffff0000u), a3);
  }
  a0 += __shfl_xor(a0, 32);             // even+odd halves -> full sums
  a1 += __shfl_xor(a1, 32);
  a2 += __shfl_xor(a2, 32);
  a3 += __shfl_xor(a3, 32);
  if (lane < 32) {
    const float o0 = a0 > 0.f ? a0 : __expf(a0) - 1.f;
    const float o1 = a1 > 0.f ? a1 : __expf(a1) - 1.f;
    const float o2 = a2 > 0.f ? a2 : __expf(a2) - 1.f;
    const float o3 = a3 > 0.f ? a3 : __expf(a3) - 1.f;
    if (LAST) {
      *(float4*)((float*)xout + (size_t)nid * HID + 4 * lane) =
          make_float4(o0, o1, o2, o3);
    } else {
      uint2 pk;
      pk.x = (unsigned)f2bf(o0) | ((unsigned)f2bf(o1) << 16);
      pk.y = (unsigned)f2bf(o2) | ((unsigned)f2bf(o3) << 16);
      *(uint2*)&((unsigned int*)xout)[(size_t)nid * (HID / 2) + 2 * lane] = pk;
    }
  }
}

__global__ __launch_bounds__(256) void attn0_kernel(
    const int* __restrict__ nb, const unsigned int* __restrict__ hbf,
    const float* __restrict__ ssrc, const float* __restrict__ sdst,
    unsigned short* __restrict__ xbf) {
  const int lane = threadIdx.x & 63;
  const int nid = (blockIdx.x << 2) + (threadIdx.x >> 6);   // 12500*4 = 50000
  attn_node<false>(nb, hbf, ssrc, sdst, (void*)xbf, lane, nid);
}

__global__ __launch_bounds__(256) void attn1_kernel(
    const int* __restrict__ nb, const unsigned int* __restrict__ hbf,
    const float* __restrict__ ssrc, const float* __restrict__ sdst,
    float* __restrict__ out) {
  const int lane = threadIdx.x & 63;
  const int nid = (blockIdx.x << 2) + (threadIdx.x >> 6);
  attn_node<true>(nb, hbf, ssrc, sdst, (void*)out, lane, nid);
}

extern "C" void kernel_launch(void* const* d_in, const int* in_sizes, int n_in,
                              void* d_out, int out_size, void* d_ws, size_t ws_size,
                              hipStream_t stream) {
  const float* feature = (const float*)d_in[0];
  const int*   nb      = (const int*)d_in[1];
  const float* pca_w   = (const float*)d_in[2];
  const float* pca_b   = (const float*)d_in[3];
  const float* Ws      = (const float*)d_in[4];
  const float* bs      = (const float*)d_in[5];
  const float* a_src   = (const float*)d_in[6];
  const float* a_dst   = (const float*)d_in[7];
  float* out = (float*)d_out;

  unsigned short* xbf = (unsigned short*)d_ws;                 // [N,128] bf16
  unsigned short* hbf = xbf + (size_t)NN * HID;                // [N,128] bf16
  float* ssrc = (float*)(hbf + (size_t)NN * HID);              // [N,8]
  float* sdst = ssrc + (size_t)NN * HH;                        // [N,8]
  unsigned short* frags = (unsigned short*)(sdst + (size_t)NN * HH); // 106496 shorts

  const int ntb = (NN / 16 + 3) / 4;      // 782 blocks, 4 tiles/block
  const int nattn = NN / 4;               // 12500 blocks, 1 node/wave
  prep_kernel<<<208, 256, 0, stream>>>(pca_w, Ws, frags);
  // Fused layer-0: x0 = relu(feat@pca_w+b); h0 = x0@W0+b0; s_src/s_dst.
  pca_proj0<<<ntb, 256, 0, stream>>>(
      feature, frags, pca_b, bs, a_src, a_dst, xbf, hbf, ssrc, sdst);
  attn0_kernel<<<nattn, 256, 0, stream>>>(nb, (const unsigned int*)hbf,
                                          ssrc, sdst, xbf);
  const unsigned short* w1 = frags + 40960 + 32768;
  proj_mfma<<<ntb, 256, 0, stream>>>(
      xbf, w1, w1 + 16384, bs + HID, a_src + HID, a_dst + HID, hbf, ssrc, sdst);
  attn1_kernel<<<nattn, 256, 0, stream>>>(nb, (const unsigned int*)hbf,
                                          ssrc, sdst, out);
}

// Round 13
// 194.427 us; speedup vs baseline: 1.0211x; 1.0211x over previous
//
#include <hip/hip_runtime.h>
#include <math.h>

#define NN 50000
#define KK 16
#define FIN 140
#define HH 8
#define HID 128

typedef __attribute__((ext_vector_type(8))) short short8;   // 8 bf16 = 4 VGPRs
typedef __attribute__((ext_vector_type(4))) float f32x4;    // MFMA acc

__device__ inline unsigned short f2bf(float f) {            // RNE fp32->bf16
  unsigned int u = __float_as_uint(f);
  return (unsigned short)((u + 0x7fffu + ((u >> 16) & 1u)) >> 16);
}
__device__ inline float bf2f(unsigned short h) {
  return __uint_as_float(((unsigned int)h) << 16);
}

// Build W^T A-operand fragment tables (hi/lo bf16 split) for pca_w and both Ws.
__global__ __launch_bounds__(256) void prep_kernel(
    const float* __restrict__ pca_w, const float* __restrict__ Ws,
    unsigned short* __restrict__ frags) {
  const int gid = blockIdx.x * 256 + threadIdx.x;   // 208*256 = 53248 exact
  const float* W; int K; unsigned short *dh, *dl; int tid;
  if (gid < 20480)      { W = pca_w;          K = FIN; dh = frags;                 dl = dh + 20480; tid = gid; }
  else if (gid < 36864) { W = Ws;             K = HID; dh = frags + 40960;         dl = dh + 16384; tid = gid - 20480; }
  else                  { W = Ws + HID * HID; K = HID; dh = frags + 40960 + 32768; dl = dh + 16384; tid = gid - 36864; }
  const int j = tid & 7, L = (tid >> 3) & 63, ct = tid >> 9, t = ct & 7, c = ct >> 3;
  const int k = c * 32 + (L >> 4) * 8 + j;
  const int col = t * 16 + (L & 15);
  const float v = (k < K) ? W[(size_t)k * HID + col] : 0.f;
  const unsigned short h = f2bf(v);
  dh[tid] = h;
  dl[tid] = f2bf(v - bf2f(h));
}

// FUSED pca -> proj0, RACE-FREE (R13). R12 failed post-timing (absmax 0.0625
// after graph replays) with the store->vmcnt(0)->reload self-sync: that was
// the only non-standard sync in the pipeline, so it is removed. Phase 2's
// B-operand is now built by a pure in-register cross-lane permutation of the
// phase-1 C-fragments (identical f2bf bits -> bit-identical output), and x0
// is never materialized in memory at all (attn0 overwrites xbf anyway):
//   target lane (col,quad), chunk c, word p <- xw[2c+(quad>>1)].{x|y by p&1}
//   from source lane col + 16*(2*(quad&1) + (p>>1)).
__global__ __launch_bounds__(256) void pca_proj0(
    const float* __restrict__ feat, const unsigned short* __restrict__ frags,
    const float* __restrict__ pca_b, const float* __restrict__ b0,
    const float* __restrict__ asrc, const float* __restrict__ adst,
    unsigned short* __restrict__ hbf, float* __restrict__ ssrc,
    float* __restrict__ sdst) {
  __shared__ short8 ldsh[512];   // 8 KB: chunk's hi frags
  __shared__ short8 ldsl[512];   // 8 KB: chunk's lo frags
  const int tid = threadIdx.x;
  const int wv = ((int)blockIdx.x << 2) + (tid >> 6);
  const bool active = wv < NN / 16;               // 782*4 = 3128, 3125 valid
  const int lane = tid & 63;
  const int col = lane & 15, quad = lane >> 4;
  const int n0 = (active ? wv : 0) * 16;
  f32x4 acc[8];
#pragma unroll
  for (int t = 0; t < 8; ++t) acc[t] = (f32x4){0.f, 0.f, 0.f, 0.f};
  // ---------------- phase 1: x0 = relu(feat @ pca_w + b) ----------------
  {
    const float* brow = feat + (size_t)(n0 + col) * FIN + quad * 8;
    const short8* gfh = (const short8*)frags;             // pca hi
    const short8* gfl = (const short8*)(frags + 20480);   // pca lo
#pragma unroll
    for (int c = 0; c < 5; ++c) {
      __syncthreads();                            // prev chunk compute done
      ldsh[tid]       = gfh[c * 512 + tid];
      ldsh[tid + 256] = gfh[c * 512 + tid + 256];
      ldsl[tid]       = gfl[c * 512 + tid];
      ldsl[tid + 256] = gfl[c * 512 + tid + 256];
      float4 a0, a1;
      if (c < 4) {
        a0 = *(const float4*)(brow + c * 32);
        a1 = *(const float4*)(brow + c * 32 + 4);
      } else {  // chunk 4: k = 128 + quad*8 + j, valid only k < 140
        a0 = make_float4(0.f, 0.f, 0.f, 0.f); a1 = a0;
        if (quad == 0) {
          a0 = *(const float4*)(brow + 128); a1 = *(const float4*)(brow + 132);
        } else if (quad == 1) {
          a0 = *(const float4*)(brow + 128);
        }
      }
      short8 B0;
      B0[0] = (short)f2bf(a0.x); B0[1] = (short)f2bf(a0.y);
      B0[2] = (short)f2bf(a0.z); B0[3] = (short)f2bf(a0.w);
      B0[4] = (short)f2bf(a1.x); B0[5] = (short)f2bf(a1.y);
      B0[6] = (short)f2bf(a1.z); B0[7] = (short)f2bf(a1.w);
      __syncthreads();                            // chunk staged
#pragma unroll
      for (int t = 0; t < 8; ++t) {
        const short8 Ah = ldsh[t * 64 + lane];
        const short8 Al = ldsl[t * 64 + lane];
        acc[t] = __builtin_amdgcn_mfma_f32_16x16x32_bf16(Al, B0, acc[t], 0, 0, 0);
        acc[t] = __builtin_amdgcn_mfma_f32_16x16x32_bf16(Ah, B0, acc[t], 0, 0, 0);
      }
    }
  }
  // pca epilogue -> packed bf16 x0 fragments IN REGISTERS (no global store).
  // xw[t].x = cols t*16+quad*4 .. +1, xw[t].y = .. +2,+3 of node n0+col.
  uint2 xw[8];
#pragma unroll
  for (int t = 0; t < 8; ++t) {
    const float4 bv = *(const float4*)(pca_b + t * 16 + quad * 4);
    const float v0 = fmaxf(acc[t][0] + bv.x, 0.f);
    const float v1 = fmaxf(acc[t][1] + bv.y, 0.f);
    const float v2 = fmaxf(acc[t][2] + bv.z, 0.f);
    const float v3 = fmaxf(acc[t][3] + bv.w, 0.f);
    xw[t].x = (unsigned)f2bf(v0) | ((unsigned)f2bf(v1) << 16);
    xw[t].y = (unsigned)f2bf(v2) | ((unsigned)f2bf(v3) << 16);
  }
  // C-frag -> B-frag cross-lane permutation (within each 4-lane column group).
  // Verified: (q=0,c=0): p0=xw[0].x@quad0=cols0,1 ... (q=3,c=1): p0=xw[3].x@quad2=cols56,57.
  short8 Bx[4];
#pragma unroll
  for (int c = 0; c < 4; ++c) {
    union { unsigned int w[4]; short8 v; } bu;
#pragma unroll
    for (int p = 0; p < 4; ++p) {
      const int src = col + 16 * (((quad & 1) << 1) + (p >> 1));
      const unsigned int lo = __shfl((p & 1) ? xw[2 * c].y     : xw[2 * c].x,     src);
      const unsigned int hi = __shfl((p & 1) ? xw[2 * c + 1].y : xw[2 * c + 1].x, src);
      bu.w[p] = (quad >> 1) ? hi : lo;
    }
    Bx[c] = bu.v;
  }
  // ---------------- phase 2: h0 = x0 @ W0 + b0; s_src/s_dst ----------------
#pragma unroll
  for (int t = 0; t < 8; ++t) acc[t] = (f32x4){0.f, 0.f, 0.f, 0.f};
  {
    const short8* gqh = (const short8*)(frags + 40960);           // W0 hi
    const short8* gql = (const short8*)(frags + 40960 + 16384);   // W0 lo
#pragma unroll
    for (int c = 0; c < 4; ++c) {
      __syncthreads();
      ldsh[tid]       = gqh[c * 512 + tid];
      ldsh[tid + 256] = gqh[c * 512 + tid + 256];
      ldsl[tid]       = gql[c * 512 + tid];
      ldsl[tid + 256] = gql[c * 512 + tid + 256];
      __syncthreads();
#pragma unroll
      for (int t = 0; t < 8; ++t) {
        const short8 Ah = ldsh[t * 64 + lane];
        const short8 Al = ldsl[t * 64 + lane];
        acc[t] = __builtin_amdgcn_mfma_f32_16x16x32_bf16(Al, Bx[c], acc[t], 0, 0, 0);
        acc[t] = __builtin_amdgcn_mfma_f32_16x16x32_bf16(Ah, Bx[c], acc[t], 0, 0, 0);
      }
    }
  }
  if (!active) return;
  // proj epilogue: lane holds node n0+col, out-cols t*16+quad*4+r (head == t)
#pragma unroll
  for (int t = 0; t < 8; ++t) {
    const float4 bv = *(const float4*)(b0 + t * 16 + quad * 4);
    const float4 av = *(const float4*)(asrc + t * 16 + quad * 4);
    const float4 dv = *(const float4*)(adst + t * 16 + quad * 4);
    const float v0 = acc[t][0] + bv.x;
    const float v1 = acc[t][1] + bv.y;
    const float v2 = acc[t][2] + bv.z;
    const float v3 = acc[t][3] + bv.w;
    uint2 pk;
    pk.x = (unsigned)f2bf(v0) | ((unsigned)f2bf(v1) << 16);
    pk.y = (unsigned)f2bf(v2) | ((unsigned)f2bf(v3) << 16);
    *(uint2*)&hbf[(size_t)(n0 + col) * HID + t * 16 + quad * 4] = pk;
    float ps = v0 * av.x + v1 * av.y + v2 * av.z + v3 * av.w;
    float pd = v0 * dv.x + v1 * dv.y + v2 * dv.z + v3 * dv.w;
    ps += __shfl_xor(ps, 16); ps += __shfl_xor(ps, 32);
    pd += __shfl_xor(pd, 16); pd += __shfl_xor(pd, 32);
    if (quad == 0) ssrc[(size_t)(n0 + col) * HH + t] = ps;
    if (quad == 1) sdst[(size_t)(n0 + col) * HH + t] = pd;
  }
}

// h = x@W + b (bf16 store); s_src/s_dst per head. LDS frag staging (layer 1).
__global__ __launch_bounds__(256) void proj_mfma(
    const unsigned short* __restrict__ xbf, const unsigned short* __restrict__ wfh,
    const unsigned short* __restrict__ wfl, const float* __restrict__ b,
    const float* __restrict__ asrc, const float* __restrict__ adst,
    unsigned short* __restrict__ hbf, float* __restrict__ ssrc,
    float* __restrict__ sdst) {
  __shared__ short8 ldsh[512];
  __shared__ short8 ldsl[512];
  const int tid = threadIdx.x;
  const int wv = ((int)blockIdx.x << 2) + (tid >> 6);
  const bool active = wv < NN / 16;
  const int lane = tid & 63;
  const int col = lane & 15, quad = lane >> 4;
  const int n0 = (active ? wv : 0) * 16;
  f32x4 acc[8];
#pragma unroll
  for (int t = 0; t < 8; ++t) acc[t] = (f32x4){0.f, 0.f, 0.f, 0.f};
  const unsigned short* brow = xbf + (size_t)(n0 + col) * HID + quad * 8;
  short8 B0[4];
#pragma unroll
  for (int c = 0; c < 4; ++c) B0[c] = *(const short8*)(brow + c * 32);
  const short8* gfh = (const short8*)wfh;
  const short8* gfl = (const short8*)wfl;
#pragma unroll
  for (int c = 0; c < 4; ++c) {
    __syncthreads();
    ldsh[tid]       = gfh[c * 512 + tid];
    ldsh[tid + 256] = gfh[c * 512 + tid + 256];
    ldsl[tid]       = gfl[c * 512 + tid];
    ldsl[tid + 256] = gfl[c * 512 + tid + 256];
    __syncthreads();
#pragma unroll
    for (int t = 0; t < 8; ++t) {
      const short8 Ah = ldsh[t * 64 + lane];
      const short8 Al = ldsl[t * 64 + lane];
      acc[t] = __builtin_amdgcn_mfma_f32_16x16x32_bf16(Al, B0[c], acc[t], 0, 0, 0);
      acc[t] = __builtin_amdgcn_mfma_f32_16x16x32_bf16(Ah, B0[c], acc[t], 0, 0, 0);
    }
  }
  if (!active) return;
  // lane holds node n0+col, out-cols t*16+quad*4+r (head == t)
#pragma unroll
  for (int t = 0; t < 8; ++t) {
    const float4 bv = *(const float4*)(b + t * 16 + quad * 4);
    const float4 av = *(const float4*)(asrc + t * 16 + quad * 4);
    const float4 dv = *(const float4*)(adst + t * 16 + quad * 4);
    const float v0 = acc[t][0] + bv.x;
    const float v1 = acc[t][1] + bv.y;
    const float v2 = acc[t][2] + bv.z;
    const float v3 = acc[t][3] + bv.w;
    uint2 pk;
    pk.x = (unsigned)f2bf(v0) | ((unsigned)f2bf(v1) << 16);
    pk.y = (unsigned)f2bf(v2) | ((unsigned)f2bf(v3) << 16);
    *(uint2*)&hbf[(size_t)(n0 + col) * HID + t * 16 + quad * 4] = pk;
    float ps = v0 * av.x + v1 * av.y + v2 * av.z + v3 * av.w;
    float pd = v0 * dv.x + v1 * dv.y + v2 * dv.z + v3 * dv.w;
    ps += __shfl_xor(ps, 16); ps += __shfl_xor(ps, 32);
    pd += __shfl_xor(pd, 16); pd += __shfl_xor(pd, 32);
    if (quad == 0) ssrc[(size_t)(n0 + col) * HH + t] = ps;
    if (quad == 1) sdst[(size_t)(n0 + col) * HH + t] = pd;
  }
}

// attn: ONE NODE per wave (R9 win). Reduction: lane = k0*8+h covers 16
// neighbors x 8 heads via xor-8/16/32 tree. 12500 blocks * 4 waves = 50000.
// R11's paired-row gather variant was neutral -> attn is at the L2/L3
// random-gather floor; this simpler form is the best-measured.
template <bool LAST>
__device__ inline void attn_node(
    const int* __restrict__ nb, const unsigned int* __restrict__ hbf,
    const float* __restrict__ ssrc, const float* __restrict__ sdst,
    void* __restrict__ xout, int lane, int nid) {
  int nbv = 0;
  if (lane < KK) nbv = nb[(size_t)nid * KK + lane];
  unsigned int u[KK];
#pragma unroll
  for (int k = 0; k < KK; ++k) {
    const int r = __shfl(nbv, k);
    u[k] = hbf[(size_t)r * (HID / 2) + lane];
  }
  const int h = lane & 7, k0 = lane >> 3;           // lane = k0*8 + h
  const int r0 = __shfl(nbv, k0), r1 = __shfl(nbv, k0 + 8);
  const float ss = ssrc[(size_t)nid * HH + h];
  float e0 = ss + sdst[(size_t)r0 * HH + h];
  float e1 = ss + sdst[(size_t)r1 * HH + h];
  e0 = e0 > 0.f ? e0 : 0.2f * e0;
  e1 = e1 > 0.f ? e1 : 0.2f * e1;
  float m = fmaxf(e0, e1);
  m = fmaxf(m, __shfl_xor(m, 8));
  m = fmaxf(m, __shfl_xor(m, 16));
  m = fmaxf(m, __shfl_xor(m, 32));
  float p0 = __expf(e0 - m), p1 = __expf(e1 - m);
  float s = p0 + p1;
  s += __shfl_xor(s, 8);
  s += __shfl_xor(s, 16);
  s += __shfl_xor(s, 32);
  const float inv = 1.f / s;
  p0 *= inv; p1 *= inv;
  const int head = lane >> 3;                       // out cols 2*lane, 2*lane+1
  float a0 = 0.f, a1 = 0.f;
#pragma unroll
  for (int k = 0; k < KK; ++k) {
    const float sel = (k < 8) ? p0 : p1;
    const float w = __shfl(sel, ((k & 7) << 3) + head);  // p[k][head]
    a0 = fmaf(w, __uint_as_float(u[k] << 16), a0);
    a1 = fmaf(w, __uint_as_float(u[k] & 0xffff0000u), a1);
  }
  const float o0 = a0 > 0.f ? a0 : __expf(a0) - 1.f;
  const float o1 = a1 > 0.f ? a1 : __expf(a1) - 1.f;
  if (LAST) {
    *(float2*)((float*)xout + (size_t)nid * HID + 2 * lane) = make_float2(o0, o1);
  } else {
    ((unsigned int*)xout)[(size_t)nid * (HID / 2) + lane] =
        (unsigned)f2bf(o0) | ((unsigned)f2bf(o1) << 16);
  }
}

__global__ __launch_bounds__(256) void attn0_kernel(
    const int* __restrict__ nb, const unsigned int* __restrict__ hbf,
    const float* __restrict__ ssrc, const float* __restrict__ sdst,
    unsigned short* __restrict__ xbf) {
  const int lane = threadIdx.x & 63;
  const int nid = (blockIdx.x << 2) + (threadIdx.x >> 6);   // 12500*4 = 50000
  attn_node<false>(nb, hbf, ssrc, sdst, (void*)xbf, lane, nid);
}

__global__ __launch_bounds__(256) void attn1_kernel(
    const int* __restrict__ nb, const unsigned int* __restrict__ hbf,
    const float* __restrict__ ssrc, const float* __restrict__ sdst,
    float* __restrict__ out) {
  const int lane = threadIdx.x & 63;
  const int nid = (blockIdx.x << 2) + (threadIdx.x >> 6);
  attn_node<true>(nb, hbf, ssrc, sdst, (void*)out, lane, nid);
}

extern "C" void kernel_launch(void* const* d_in, const int* in_sizes, int n_in,
                              void* d_out, int out_size, void* d_ws, size_t ws_size,
                              hipStream_t stream) {
  const float* feature = (const float*)d_in[0];
  const int*   nb      = (const int*)d_in[1];
  const float* pca_w   = (const float*)d_in[2];
  const float* pca_b   = (const float*)d_in[3];
  const float* Ws      = (const float*)d_in[4];
  const float* bs      = (const float*)d_in[5];
  const float* a_src   = (const float*)d_in[6];
  const float* a_dst   = (const float*)d_in[7];
  float* out = (float*)d_out;

  unsigned short* xbf = (unsigned short*)d_ws;                 // [N,128] bf16
  unsigned short* hbf = xbf + (size_t)NN * HID;                // [N,128] bf16
  float* ssrc = (float*)(hbf + (size_t)NN * HID);              // [N,8]
  float* sdst = ssrc + (size_t)NN * HH;                        // [N,8]
  unsigned short* frags = (unsigned short*)(sdst + (size_t)NN * HH); // 106496 shorts

  const int ntb = (NN / 16 + 3) / 4;      // 782 blocks, 4 tiles/block
  const int nattn = NN / 4;               // 12500 blocks, 1 node/wave
  prep_kernel<<<208, 256, 0, stream>>>(pca_w, Ws, frags);
  // Fused layer-0 (race-free: x0 never touches memory; in-register permute).
  pca_proj0<<<ntb, 256, 0, stream>>>(
      feature, frags, pca_b, bs, a_src, a_dst, hbf, ssrc, sdst);
  attn0_kernel<<<nattn, 256, 0, stream>>>(nb, (const unsigned int*)hbf,
                                          ssrc, sdst, xbf);
  const unsigned short* w1 = frags + 40960 + 32768;
  proj_mfma<<<ntb, 256, 0, stream>>>(
      xbf, w1, w1 + 16384, bs + HID, a_src + HID, a_dst + HID, hbf, ssrc, sdst);
  attn1_kernel<<<nattn, 256, 0, stream>>>(nb, (const unsigned int*)hbf,
                                          ssrc, sdst, out);
}